// Round 7
// baseline (328.360 us; speedup 1.0000x reference)
//
#include <hip/hip_runtime.h>
#include <stdint.h>

// Problem constants (fixed by the reference)
#define N_TOK 8192
#define IN_F 4096
#define OUT_F 4096
#define BS 256
#define ABPI 5
#define NFLAT 80          // 16 output blocks x 5 slots = all (g,a) pairs

typedef __attribute__((ext_vector_type(8))) short short8;    // 8 bf16 = 4 VGPRs (MFMA A/B frag)
typedef __attribute__((ext_vector_type(4))) float floatx4;   // MFMA C/D frag
typedef __attribute__((ext_vector_type(4))) unsigned short ushort4v;

__device__ __forceinline__ unsigned short f2bf(float f) {
  union { float f; unsigned int u; } v; v.f = f;
  unsigned int r = v.u + 0x7FFFu + ((v.u >> 16) & 1u);   // RNE
  return (unsigned short)(r >> 16);
}

__device__ __forceinline__ void async16(const void* g, void* l) {
  __builtin_amdgcn_global_load_lds((const __attribute__((address_space(1))) void*)g,
                                   (__attribute__((address_space(3))) void*)l, 16, 0, 0);
}

// ---------------- kernel 1: x fp32 -> bf16 (pure-coalesced grid-stride) -------
__global__ void cvt_x_kernel(const float4* __restrict__ x, ushort4v* __restrict__ xb) {
  int idx = blockIdx.x * 256 + threadIdx.x;       // one float4 -> ushort4 per iter
  const int stride = 2048 * 256;
  #pragma unroll
  for (int i = 0; i < 16; ++i, idx += stride) {   // 8192*4096/4 = 16 * 2048*256
    float4 a = x[idx];
    ushort4v o;
    o[0] = f2bf(a.x); o[1] = f2bf(a.y); o[2] = f2bf(a.z); o[3] = f2bf(a.w);
    xb[idx] = o;
  }
}

// ---------------- kernel 2: weight fp32 -> bf16, transposed per (g,a) block ----
__global__ void cvt_w_kernel(const float* __restrict__ w, unsigned short* __restrict__ wt) {
  __shared__ unsigned short tile[64][68];
  int b = blockIdx.x;
  int fi = b >> 4;
  int t  = b & 15;
  int k0 = (t >> 2) * 64, o0 = (t & 3) * 64;
  int g = fi / ABPI, a = fi % ABPI;
  int tid = threadIdx.x;
  int tr = tid >> 4, tc = tid & 15;
  #pragma unroll
  for (int i = 0; i < 4; ++i) {
    int k = k0 + i * 16 + tr;
    const float* src = w + (size_t)(g * 256 + k) * (ABPI * BS) + a * BS + o0 + tc * 4;
    float4 v = *(const float4*)src;
    tile[tc * 4 + 0][i * 16 + tr] = f2bf(v.x);
    tile[tc * 4 + 1][i * 16 + tr] = f2bf(v.y);
    tile[tc * 4 + 2][i * 16 + tr] = f2bf(v.z);
    tile[tc * 4 + 3][i * 16 + tr] = f2bf(v.w);
  }
  __syncthreads();
  #pragma unroll
  for (int i = 0; i < 4; ++i) {
    int o = i * 16 + tr;
    unsigned short* dst = wt + (size_t)fi * (BS * BS) + (size_t)(o0 + o) * BS + k0 + tc * 4;
    *(ushort4v*)dst = *(const ushort4v*)&tile[o][tc * 4];
  }
}

// ---------------- kernel 3: butterfly block-sparse GEMM, m201 8-phase port -----
// 256x256 tile, 8 waves (2M x 4N), per-wave 128x64, BK=64, double-buffered LDS.
// Per K-tile: 4 phases, each {window: 2 stage issues + ds_reads} bar lgkm
// setprio1 16xMFMA setprio0 bar. Stage slots placed by LDS region death:
//   W1: B-half0(t+1) -> buf^1.B   (whole B of t-1 dead since prior tile)
//   W2: B-half1(t+1) -> buf^1.B
//   W3: A-even(t+2)  -> buf.A rows 0-63,128-191 (dead after P1-close)
//   W4: A-odd(t+2)   -> buf.A rows 64-127,192-255 (dead after P3-close)
// Tile-end: vmcnt(4) (drains A(t+1)+B(t+1)=8 oldest, leaves A(t+2) in flight —
// counted, never 0 until t=18). Reads: W1 = A-sub0(8)+B01(4)+B23(4), W3 =
// A-sub1(8); B frags live in regs across the whole tile (24 reads/tile/wave).
// Hazard proof: tile t's reads certified done chip-wide at P1/P3-close bars;
// every stage lands >=1 vmcnt+bar before its first reader (induction ledger).

#define BM 256
#define BN 256
#define BK 64
#define ABYTES 32768              // 256 rows x 128 B
#define BUFBYTES 65536            // A + B
#define SMEM_TOTAL 131072         // 2 buffers

#define SB() __builtin_amdgcn_sched_barrier(0)
#define PRIO1() __builtin_amdgcn_s_setprio(1)
#define PRIO0() __builtin_amdgcn_s_setprio(0)
#define BARRIER() __builtin_amdgcn_s_barrier()
#define LGKM0() do { asm volatile("s_waitcnt lgkmcnt(0)" ::: "memory"); SB(); } while (0)

__device__ __forceinline__ void ld_half_A(const char* p, int c0, int c1, short8 (&af)[4][2]) {
  #pragma unroll
  for (int mt = 0; mt < 4; ++mt) {
    const char* q = p + mt * 2048;
    af[mt][0] = *(const short8*)(q + c0);
    af[mt][1] = *(const short8*)(q + c1);
  }
}

__device__ __forceinline__ void ld_pair_B(const char* p, int c0, int c1, short8 (&bf)[2][2]) {
  #pragma unroll
  for (int nt = 0; nt < 2; ++nt) {
    const char* q = p + nt * 2048;
    bf[nt][0] = *(const short8*)(q + c0);
    bf[nt][1] = *(const short8*)(q + c1);
  }
}

__device__ __forceinline__ void mma16(const short8 (&af)[4][2], const short8 (&bf)[2][2],
                                      floatx4 (&acc)[8][4], int mb, int nb) {
  #pragma unroll
  for (int mt = 0; mt < 4; ++mt)
    #pragma unroll
    for (int nt = 0; nt < 2; ++nt) {
      acc[mb + mt][nb + nt] =
          __builtin_amdgcn_mfma_f32_16x16x32_bf16(af[mt][0], bf[nt][0], acc[mb + mt][nb + nt], 0, 0, 0);
      acc[mb + mt][nb + nt] =
          __builtin_amdgcn_mfma_f32_16x16x32_bf16(af[mt][1], bf[nt][1], acc[mb + mt][nb + nt], 0, 0, 0);
    }
}

// END: 2 = vmcnt(4)+bar (steady), 1 = vmcnt(0)+bar (t=18), 0 = none (t=19)
#define KTILE(Ab, Bb, Bsd, uB, uA2, STB, STA, END)                              \
  do {                                                                          \
    /* ---- W1: stage B-half0(t+1); read A-sub0 + all B ---- */                 \
    if (STB) { async16(pB0 + (uB), (Bsd)         + tid16);                      \
               async16(pB1 + (uB), (Bsd) +  8192 + tid16); }                    \
    ld_half_A((Ab) + rAb,        c0, c1, af);                                   \
    ld_pair_B((Bb) + rBb,        c0, c1, bf01);                                 \
    ld_pair_B((Bb) + rBb + 4096, c0, c1, bf23);                                 \
    SB(); BARRIER(); LGKM0();                                                   \
    PRIO1(); mma16(af, bf01, acc, 0, 0); PRIO0();                               \
    BARRIER();                                                                  \
    /* ---- W2: stage B-half1(t+1) ---- */                                      \
    if (STB) { async16(pB2 + (uB), (Bsd) + 16384 + tid16);                      \
               async16(pB3 + (uB), (Bsd) + 24576 + tid16); }                    \
    SB(); BARRIER();                                                            \
    PRIO1(); mma16(af, bf23, acc, 0, 2); PRIO0();                               \
    BARRIER();                                                                  \
    /* ---- W3: stage A-even(t+2) into dead rows of CURRENT buf; read A-sub1 */ \
    if (STA) { async16(pA0 + (uA2), (Ab)         + tid16);                      \
               async16(pA2 + (uA2), (Ab) + 16384 + tid16); }                    \
    ld_half_A((Ab) + rAb + 8192, c0, c1, af);                                   \
    SB(); BARRIER(); LGKM0();                                                   \
    PRIO1(); mma16(af, bf23, acc, 4, 2); PRIO0();                               \
    BARRIER();                                                                  \
    /* ---- W4: stage A-odd(t+2) ---- */                                        \
    if (STA) { async16(pA1 + (uA2), (Ab) +  8192 + tid16);                      \
               async16(pA3 + (uA2), (Ab) + 24576 + tid16); }                    \
    SB(); BARRIER();                                                            \
    PRIO1(); mma16(af, bf01, acc, 4, 0); PRIO0();                               \
    if ((END) == 2)      { asm volatile("s_waitcnt vmcnt(4)" ::: "memory");     \
                           SB(); BARRIER(); }                                   \
    else if ((END) == 1) { asm volatile("s_waitcnt vmcnt(0)" ::: "memory");     \
                           SB(); BARRIER(); }                                   \
  } while (0)

__global__ __launch_bounds__(512, 2)
void bfly_gemm(const unsigned short* __restrict__ xb,   // [8192][4096] bf16
               const unsigned short* __restrict__ wt,   // [80][256 o][256 k] bf16
               const int* __restrict__ fidx,            // [16][5]
               float* __restrict__ out)                 // [8192][4096] fp32
{
  extern __shared__ __align__(16) char smem[];
  char* const b0A = smem;
  char* const b0B = b0A + ABYTES;
  char* const b1A = smem + BUFBYTES;
  char* const b1B = b1A + ABYTES;

  const int tid = threadIdx.x;
  // 512 blocks; bijective XCD swizzle (512 % 8 == 0)
  const int bx  = blockIdx.x;
  const int swz = (bx & 7) * 64 + (bx >> 3);
  const int ob  = swz >> 5;            // 0..15
  const int mt0 = swz & 31;            // 0..31
  const int m0  = mt0 * BM;
  const int n0g = ob * 256;

  int wbase[ABPI], gcol[ABPI];
  #pragma unroll
  for (int s = 0; s < ABPI; ++s) {
    int fi = __builtin_amdgcn_readfirstlane(fidx[ob * ABPI + s]);  // fi = g*5 + a
    wbase[s] = fi * (BS * BS);
    gcol[s]  = (fi / ABPI) * BS;
  }

  // staging constants: each issue covers 64 rows x 8 chunks of 16 B; logical
  // k-chunk lc staged at physical slot sc with lc = sc ^ (row&7) (0-conflict)
  const int sr = tid >> 3;
  const int sc = tid & 7;
  const int lc = sc ^ (sr & 7);
  const int tid16 = tid * 16;
  const unsigned short* pA0 = xb + (size_t)(m0 +   0 + sr) * IN_F + lc * 8;
  const unsigned short* pA1 = xb + (size_t)(m0 +  64 + sr) * IN_F + lc * 8;
  const unsigned short* pA2 = xb + (size_t)(m0 + 128 + sr) * IN_F + lc * 8;
  const unsigned short* pA3 = xb + (size_t)(m0 + 192 + sr) * IN_F + lc * 8;
  const unsigned short* pB0 = wt + (  0 + sr) * BS + lc * 8;
  const unsigned short* pB1 = wt + ( 64 + sr) * BS + lc * 8;
  const unsigned short* pB2 = wt + (128 + sr) * BS + lc * 8;
  const unsigned short* pB3 = wt + (192 + sr) * BS + lc * 8;

  // fragment-read constants: 8 waves 2M x 4N; per-wave 128 m x 64 n
  const int lane = tid & 63;
  const int wv   = tid >> 6;
  const int wm   = (wv >> 2) * 128;    // 0 or 128
  const int wn   = (wv & 3) * 64;      // 0,64,128,192
  const int lrow = lane & 15;
  const int quad = lane >> 4;
  const int rAb  = (wm + lrow) * 128;  // byte; A row stride 128 B
  const int rBb  = (wn + lrow) * 128;
  const int c0   = ((quad)     ^ (lrow & 7)) * 16;
  const int c1   = ((quad + 4) ^ (lrow & 7)) * 16;

  short8 af[4][2], bf01[2][2], bf23[2][2];
  floatx4 acc[8][4] = {};

  // ---- prologue: stage T0 fully (buf0) + A(T1) (buf1); drain T0, keep A(T1) --
  {
    const int uA0 = gcol[0], uB0 = wbase[0], uA1 = gcol[0] + 64;
    async16(pA0 + uA0, b0A         + tid16);
    async16(pA1 + uA0, b0A +  8192 + tid16);
    async16(pA2 + uA0, b0A + 16384 + tid16);
    async16(pA3 + uA0, b0A + 24576 + tid16);
    async16(pB0 + uB0, b0B         + tid16);
    async16(pB1 + uB0, b0B +  8192 + tid16);
    async16(pB2 + uB0, b0B + 16384 + tid16);
    async16(pB3 + uB0, b0B + 24576 + tid16);
    SB();
    async16(pA0 + uA1, b1A         + tid16);
    async16(pA1 + uA1, b1A +  8192 + tid16);
    async16(pA2 + uA1, b1A + 16384 + tid16);
    async16(pA3 + uA1, b1A + 24576 + tid16);
    asm volatile("s_waitcnt vmcnt(4)" ::: "memory");   // T0 done; A(T1) in flight
    SB();
    BARRIER();
  }

  // ---- main loop: 20 K-tiles; tile t: stage B(t+1), A(t+2) ----
  // t=4g+0: B@wb[g]+64,  A@gc[g]+128 | t=4g+1: B@wb[g]+128, A@gc[g]+192
  // t=4g+2: B@wb[g]+192, A@gc[g+1]   | t=4g+3: B@wb[g+1],   A@gc[g+1]+64
  #pragma unroll 1
  for (int g = 0; g < 4; ++g) {
    const int wbg = wbase[g], gcg = gcol[g];
    const int wbn = wbase[g + 1], gcn = gcol[g + 1];
    KTILE(b0A, b0B, b1B, wbg +  64, gcg + 128, 1, 1, 2);
    KTILE(b1A, b1B, b0B, wbg + 128, gcg + 192, 1, 1, 2);
    KTILE(b0A, b0B, b1B, wbg + 192, gcn,       1, 1, 2);
    KTILE(b1A, b1B, b0B, wbn,       gcn +  64, 1, 1, 2);
  }
  { // group 4: tiles 16..19
    const int wbg = wbase[4], gcg = gcol[4];
    KTILE(b0A, b0B, b1B, wbg +  64, gcg + 128, 1, 1, 2);
    KTILE(b1A, b1B, b0B, wbg + 128, gcg + 192, 1, 1, 2);
    KTILE(b0A, b0B, b1B, wbg + 192, 0,         1, 0, 1);  // t=18: B(19) only, drain all
    KTILE(b1A, b1B, b0B, 0,         0,         0, 0, 0);  // t=19: compute only
  }

  // ---- epilogue: C/D layout col=lane&15, row=quad*4+reg (m89-verified) ----
  #pragma unroll
  for (int m = 0; m < 8; ++m) {
    const int row = m0 + wm + (m >> 2) * 64 + (m & 3) * 16 + quad * 4;
    #pragma unroll
    for (int n = 0; n < 4; ++n) {
      const int col = n0g + wn + n * 16 + lrow;
      float* po = out + (size_t)row * OUT_F + col;
      #pragma unroll
      for (int r = 0; r < 4; ++r)
        po[(size_t)r * OUT_F] = acc[m][n][r];
    }
  }
}

extern "C" void kernel_launch(void* const* d_in, const int* in_sizes, int n_in,
                              void* d_out, int out_size, void* d_ws, size_t ws_size,
                              hipStream_t stream) {
  const float* x  = (const float*)d_in[0];          // [8192][4096]
  const float* w  = (const float*)d_in[1];          // [4096][5][256]
  const int* fidx = (const int*)d_in[2];            // [16][5]
  float* out = (float*)d_out;

  unsigned short* xb = (unsigned short*)d_ws;
  unsigned short* wt = xb + (size_t)N_TOK * IN_F;

  static int smem_set = 0;
  if (!smem_set) {
    hipFuncSetAttribute((const void*)bfly_gemm,
                        hipFuncAttributeMaxDynamicSharedMemorySize, SMEM_TOTAL);
    smem_set = 1;
  }

  cvt_x_kernel<<<2048, 256, 0, stream>>>((const float4*)x, (ushort4v*)xb);
  cvt_w_kernel<<<NFLAT * 16, 256, 0, stream>>>(w, wt);
  bfly_gemm<<<16 * 32, 512, SMEM_TOTAL, stream>>>(xb, wt, fidx, out);
}